// Round 6
// baseline (313.164 us; speedup 1.0000x reference)
//
#include <hip/hip_runtime.h>
#include <stdint.h>

#define BB 2
#define TT 2048
#define CCx 1024
#define HH 16
#define DD 64
#define MM (BB*TT)      // 4096
#define C3 (3*CCx)      // 3072

using u16 = unsigned short;
typedef __attribute__((ext_vector_type(8))) short short8;
typedef __attribute__((ext_vector_type(4))) float f32x4;

__device__ __forceinline__ float bf2f(u16 u){
  union { unsigned int i; float f; } v; v.i = ((unsigned int)u) << 16; return v.f;
}
__device__ __forceinline__ u16 f2bf(float f){
  union { float f; unsigned int u; } v; v.f = f;
  unsigned int r = v.u + 0x7fffu + ((v.u >> 16) & 1u);
  return (u16)(r >> 16);
}

// D = A(16x32)*B(32x16)+C, bf16 in, fp32 out.
// A-frag: lane holds A[lane&15][8*(lane>>4)+i]; B-frag: lane holds B[8g+i][lane&15]
// C/D: lane holds D[4*(lane>>4)+r][lane&15]
__device__ __forceinline__ f32x4 mfma16x16x32(short8 a, short8 b, f32x4 c){
  return __builtin_amdgcn_mfma_f32_16x16x32_bf16(a, b, c, 0, 0, 0);
}

typedef __attribute__((address_space(1))) unsigned int gu32;
typedef __attribute__((address_space(3))) unsigned int su32;
__device__ __forceinline__ void gload16(const void* g, void* l){
  __builtin_amdgcn_global_load_lds((gu32*)g, (su32*)l, 16, 0, 0);
}

// ---------------- x convert: f32 -> bf16 ----------------
__global__ __launch_bounds__(256) void cvt_x_k(const float* __restrict__ inv,
                                               u16* __restrict__ out, int n8){
  int i = blockIdx.x*256 + threadIdx.x;
  if (i >= n8) return;
  const float* p = inv + (size_t)i*8;
  float4 a = *(const float4*)p, b = *(const float4*)(p+4);
  short8 v;
  v[0]=(short)f2bf(a.x); v[1]=(short)f2bf(a.y); v[2]=(short)f2bf(a.z); v[3]=(short)f2bf(a.w);
  v[4]=(short)f2bf(b.x); v[5]=(short)f2bf(b.y); v[6]=(short)f2bf(b.z); v[7]=(short)f2bf(b.w);
  *(short8*)(out + (size_t)i*8) = v;
}

// ------- padded transpose+convert: in[R][Cc] f32 -> out[Cc][R] bf16 -----
__global__ __launch_bounds__(256) void transpose_cvt_k(const float* __restrict__ inv,
                                                       u16* __restrict__ out,
                                                       int R, int Cc){
  __shared__ u16 t[64][65];
  const int bx = blockIdx.x*64, by = blockIdx.y*64;
  const int tx = threadIdx.x & 63, ty = threadIdx.x >> 6;
  #pragma unroll
  for (int i = 0; i < 16; ++i){
    int r = ty + i*4;
    t[r][tx] = f2bf(inv[(size_t)(by+r)*Cc + bx+tx]);
  }
  __syncthreads();
  #pragma unroll
  for (int i = 0; i < 16; ++i){
    int r = ty + i*4;
    out[(size_t)(bx+r)*R + by+tx] = t[tx][r];
  }
}

// ---------------- GEMM (NT): C[M][N] = A[M][K]*BT[N][K]^T + bias ----------
// 128x128 tile, BK=64, 4 waves (64x64 each). of32: 1 = write float, 0 = bf16.
__global__ __launch_bounds__(256) void gemm_nt(const u16* __restrict__ A,
                                               const u16* __restrict__ BT,
                                               const float* __restrict__ bias,
                                               void* __restrict__ Cmat,
                                               int M, int N, int K, int of32){
  __shared__ u16 lA[128*64];
  __shared__ u16 lB[128*64];
  const int tid  = threadIdx.x;
  const int lane = tid & 63;
  const int wave = tid >> 6;
  const int bm = blockIdx.x, bn = blockIdx.y;
  const int wm = (wave >> 1) * 64;
  const int wn = (wave & 1) * 64;
  const int ln15 = lane & 15, g = lane >> 4;

  f32x4 acc[4][4];
  #pragma unroll
  for (int i = 0; i < 4; ++i)
    #pragma unroll
    for (int j = 0; j < 4; ++j) acc[i][j] = (f32x4){0.f,0.f,0.f,0.f};

  // staging: chunk = c*256+tid; phys row = chunk>>3; phys col (tid&7) holds
  // logical col (tid&7)^(row&7)  [both-sides involution, 16B granular]
  const int trow = tid >> 3;
  const int tc8s = (tid & 7) ^ (trow & 7);
  const size_t arow0 = (size_t)(bm*128) * K;
  const size_t brow0 = (size_t)(bn*128) * K;

  for (int k0 = 0; k0 < K; k0 += 64) {
    __syncthreads();
    #pragma unroll
    for (int c = 0; c < 4; ++c) {
      const int row = c*32 + trow;
      const size_t roff = (size_t)row*K + k0 + tc8s*8;
      gload16(A + arow0 + roff, (char*)lA + (c*256 + (wave<<6))*16);
      gload16(BT + brow0 + roff, (char*)lB + (c*256 + (wave<<6))*16);
    }
    asm volatile("s_waitcnt vmcnt(0)" ::: "memory");
    __syncthreads();

    short8 af[4][2], bfr[4][2];
    #pragma unroll
    for (int mf = 0; mf < 4; ++mf)
      #pragma unroll
      for (int kc = 0; kc < 2; ++kc) {
        const int r = wm + mf*16 + ln15;
        const int cb = (kc*64 + (g << 4)) ^ ((r & 7) << 4);
        af[mf][kc] = *(const short8*)((const char*)lA + r*128 + cb);
      }
    #pragma unroll
    for (int nf = 0; nf < 4; ++nf)
      #pragma unroll
      for (int kc = 0; kc < 2; ++kc) {
        const int r = wn + nf*16 + ln15;
        const int cb = (kc*64 + (g << 4)) ^ ((r & 7) << 4);
        bfr[nf][kc] = *(const short8*)((const char*)lB + r*128 + cb);
      }
    #pragma unroll
    for (int kc = 0; kc < 2; ++kc)
      #pragma unroll
      for (int mf = 0; mf < 4; ++mf)
        #pragma unroll
        for (int nf = 0; nf < 4; ++nf)
          acc[mf][nf] = mfma16x16x32(af[mf][kc], bfr[nf][kc], acc[mf][nf]);
  }

  #pragma unroll
  for (int nf = 0; nf < 4; ++nf) {
    const int col = bn*128 + wn + nf*16 + ln15;
    const float bv = bias[col];
    #pragma unroll
    for (int mf = 0; mf < 4; ++mf) {
      #pragma unroll
      for (int r = 0; r < 4; ++r) {
        const int rowg = bm*128 + wm + mf*16 + g*4 + r;
        const float v = acc[mf][nf][r] + bv;
        if (of32) ((float*)Cmat)[(size_t)rowg*N + col] = v;
        else      ((u16*)Cmat)[(size_t)rowg*N + col] = f2bf(v);
      }
    }
  }
}

// ---------------- causal flash attention ----------------
// grid: (T/64, B*H); block 256 = 4 waves; wave handles 16 q-rows
__global__ __launch_bounds__(256) void attn_k(const u16* __restrict__ qkv,
                                              u16* __restrict__ y){
  __shared__ u16 vT[64*80];      // [d][key], stride 160B, chunk-XOR swizzled
  __shared__ u16 pl[4][16*80];   // per-wave P [qrow][key], same swizzle
  const int tid  = threadIdx.x;
  const int lane = tid & 63;
  const int wave = tid >> 6;
  const int qb = (gridDim.x - 1) - blockIdx.x;   // heavy blocks launch first
  const int bh = blockIdx.y;
  const int b = bh >> 4, h = bh & 15;
  const int ln15 = lane & 15, g = lane >> 4;

  const int q0 = qb*64 + wave*16;
  const size_t qkbase = (size_t)b * TT * C3;

  short8 qf[2];
  {
    const u16* qp = qkv + qkbase + (size_t)(q0 + ln15)*C3 + h*DD + g*8;
    qf[0] = *(const short8*)qp;
    qf[1] = *(const short8*)(qp + 32);
  }

  f32x4 o[4]; float m[4], lsum[4];
  #pragma unroll
  for (int i = 0; i < 4; ++i){ o[i] = (f32x4){0.f,0.f,0.f,0.f}; m[i] = -1e30f; lsum[i] = 0.f; }

  const int ntile = qb + 1;
  for (int t = 0; t < ntile; ++t) {
    const int kv0 = t*64;
    __syncthreads();
    #pragma unroll
    for (int it = 0; it < 2; ++it) {
      int idx = it*256 + tid;
      int key = idx >> 3, c8 = idx & 7;
      short8 v = *(const short8*)(qkv + qkbase + (size_t)(kv0 + key)*C3 + 2*CCx + h*DD + c8*8);
      #pragma unroll
      for (int i = 0; i < 8; ++i) {
        int d = c8*8 + i;
        *(u16*)((char*)vT + d*160 + (((key >> 3) ^ (d & 7)) << 4) + (key & 7)*2) = (u16)v[i];
      }
    }
    __syncthreads();

    f32x4 s[4];
    #pragma unroll
    for (int kf = 0; kf < 4; ++kf) {
      const u16* kp = qkv + qkbase + (size_t)(kv0 + kf*16 + ln15)*C3 + CCx + h*DD + g*8;
      short8 k0 = *(const short8*)kp;
      short8 k1 = *(const short8*)(kp + 32);
      f32x4 z = (f32x4){0.f,0.f,0.f,0.f};
      s[kf] = mfma16x16x32(qf[0], k0, z);
      s[kf] = mfma16x16x32(qf[1], k1, s[kf]);
    }

    float sv[4][4];
    float tmax[4] = {-1e30f,-1e30f,-1e30f,-1e30f};
    #pragma unroll
    for (int kf = 0; kf < 4; ++kf) {
      const int key = kv0 + kf*16 + ln15;
      #pragma unroll
      for (int r = 0; r < 4; ++r) {
        const int q = q0 + g*4 + r;
        float v = s[kf][r] * 0.125f;
        v = (key <= q) ? v : -1e30f;
        sv[kf][r] = v;
        tmax[r] = fmaxf(tmax[r], v);
      }
    }
    #pragma unroll
    for (int r = 0; r < 4; ++r) {
      float v = tmax[r];
      v = fmaxf(v, __shfl_xor(v, 1));
      v = fmaxf(v, __shfl_xor(v, 2));
      v = fmaxf(v, __shfl_xor(v, 4));
      v = fmaxf(v, __shfl_xor(v, 8));
      tmax[r] = v;
    }
    float fac[4], rsum[4];
    #pragma unroll
    for (int r = 0; r < 4; ++r) {
      const float nm = fmaxf(m[r], tmax[r]);
      fac[r] = exp2f((m[r] - nm) * 1.44269504f);
      m[r] = nm;
      rsum[r] = 0.f;
    }
    #pragma unroll
    for (int kf = 0; kf < 4; ++kf)
      #pragma unroll
      for (int r = 0; r < 4; ++r) {
        const float p = exp2f((sv[kf][r] - m[r]) * 1.44269504f);
        rsum[r] += p;
        const int qr = g*4 + r;
        const int col = kf*16 + ln15;
        *(u16*)((char*)&pl[wave][0] + qr*160 + (((col >> 3) ^ (qr & 7)) << 4) + (col & 7)*2) = f2bf(p);
      }
    #pragma unroll
    for (int r = 0; r < 4; ++r) {
      float v = rsum[r];
      v += __shfl_xor(v, 1);
      v += __shfl_xor(v, 2);
      v += __shfl_xor(v, 4);
      v += __shfl_xor(v, 8);
      lsum[r] = lsum[r] * fac[r] + v;
      #pragma unroll
      for (int db = 0; db < 4; ++db) o[db][r] *= fac[r];
    }
    asm volatile("s_waitcnt lgkmcnt(0)" ::: "memory");
    __builtin_amdgcn_sched_barrier(0);

    #pragma unroll
    for (int kc = 0; kc < 2; ++kc) {
      const int ch = kc*4 + g;
      short8 pa = *(const short8*)((const char*)&pl[wave][0] + ln15*160 + ((ch ^ (ln15 & 7)) << 4));
      #pragma unroll
      for (int db = 0; db < 4; ++db) {
        const int vd = db*16 + ln15;
        short8 vb = *(const short8*)((const char*)vT + vd*160 + ((ch ^ (vd & 7)) << 4));
        o[db] = mfma16x16x32(pa, vb, o[db]);
      }
    }
  }

  float inv[4];
  #pragma unroll
  for (int r = 0; r < 4; ++r) inv[r] = 1.0f / lsum[r];
  #pragma unroll
  for (int db = 0; db < 4; ++db) {
    #pragma unroll
    for (int r = 0; r < 4; ++r) {
      y[(size_t)(b*TT + q0 + g*4 + r)*CCx + h*DD + db*16 + ln15] = f2bf(o[db][r] * inv[r]);
    }
  }
}

extern "C" void kernel_launch(void* const* d_in, const int* in_sizes, int n_in,
                              void* d_out, int out_size, void* d_ws, size_t ws_size,
                              hipStream_t stream) {
  // bind inputs by element count (all distinct) — immune to ordering
  const float *x = nullptr, *w_attn = nullptr, *b_attn = nullptr,
              *w_proj = nullptr, *b_proj = nullptr;
  for (int i = 0; i < n_in; ++i) {
    switch (in_sizes[i]) {
      case MM*CCx:  x      = (const float*)d_in[i]; break;  // 4194304
      case C3*CCx:  w_attn = (const float*)d_in[i]; break;  // 3145728
      case C3:      b_attn = (const float*)d_in[i]; break;  // 3072
      case CCx*CCx: w_proj = (const float*)d_in[i]; break;  // 1048576
      case CCx:     b_proj = (const float*)d_in[i]; break;  // 1024
    }
  }
  float* out = (float*)d_out;   // reference output dtype is float32

  char* ws = (char*)d_ws;
  u16* xb      = (u16*)ws;                              // [4096][1024] bf16
  u16* wT_attn = xb + (size_t)MM*CCx;                   // [3072][1024]
  u16* wT_proj = wT_attn + (size_t)C3*CCx;              // [1024][1024]
  u16* qkv     = wT_proj + (size_t)CCx*CCx;             // [4096][3072]
  u16* ybuf    = qkv + (size_t)MM*C3;                   // [4096][1024]

  cvt_x_k<<<(MM*CCx/8 + 255)/256, 256, 0, stream>>>(x, xb, MM*CCx/8);
  transpose_cvt_k<<<dim3(C3/64, CCx/64), 256, 0, stream>>>(w_attn, wT_attn, CCx, C3);
  transpose_cvt_k<<<dim3(CCx/64, CCx/64), 256, 0, stream>>>(w_proj, wT_proj, CCx, CCx);
  gemm_nt<<<dim3(MM/128, C3/128), 256, 0, stream>>>(xb, wT_attn, b_attn, qkv, MM, C3, CCx, 0);
  attn_k<<<dim3(TT/64, BB*HH), 256, 0, stream>>>(qkv, ybuf);
  gemm_nt<<<dim3(MM/128, CCx/128), 256, 0, stream>>>(ybuf, wT_proj, b_proj, out, MM, CCx, CCx, 1);
}

// Round 7
// 211.630 us; speedup vs baseline: 1.4798x; 1.4798x over previous
//
#include <hip/hip_runtime.h>
#include <stdint.h>

#define BB 2
#define TT 2048
#define CCx 1024
#define HH 16
#define DD 64
#define MM (BB*TT)      // 4096
#define C3 (3*CCx)      // 3072

using u16 = unsigned short;
typedef __attribute__((ext_vector_type(8))) short short8;
typedef __attribute__((ext_vector_type(4))) float f32x4;

__device__ __forceinline__ float bf2f(u16 u){
  union { unsigned int i; float f; } v; v.i = ((unsigned int)u) << 16; return v.f;
}
__device__ __forceinline__ u16 f2bf(float f){
  union { float f; unsigned int u; } v; v.f = f;
  unsigned int r = v.u + 0x7fffu + ((v.u >> 16) & 1u);
  return (u16)(r >> 16);
}

// D = A(16x32)*B(32x16)+C, bf16 in, fp32 out.
// A-frag: lane holds A[lane&15][8*(lane>>4)+i]; B-frag: lane holds B[8g+i][lane&15]
// C/D: lane holds D[4*(lane>>4)+r][lane&15]
__device__ __forceinline__ f32x4 mfma16x16x32(short8 a, short8 b, f32x4 c){
  return __builtin_amdgcn_mfma_f32_16x16x32_bf16(a, b, c, 0, 0, 0);
}

typedef __attribute__((address_space(1))) unsigned int gu32;
typedef __attribute__((address_space(3))) unsigned int su32;
__device__ __forceinline__ void gload16(const void* g, void* l){
  __builtin_amdgcn_global_load_lds((gu32*)g, (su32*)l, 16, 0, 0);
}

// ---------------- x convert: f32 -> bf16 ----------------
__global__ __launch_bounds__(256) void cvt_x_k(const float* __restrict__ inv,
                                               u16* __restrict__ out, int n8){
  int i = blockIdx.x*256 + threadIdx.x;
  if (i >= n8) return;
  const float* p = inv + (size_t)i*8;
  float4 a = *(const float4*)p, b = *(const float4*)(p+4);
  short8 v;
  v[0]=(short)f2bf(a.x); v[1]=(short)f2bf(a.y); v[2]=(short)f2bf(a.z); v[3]=(short)f2bf(a.w);
  v[4]=(short)f2bf(b.x); v[5]=(short)f2bf(b.y); v[6]=(short)f2bf(b.z); v[7]=(short)f2bf(b.w);
  *(short8*)(out + (size_t)i*8) = v;
}

// ------- padded transpose+convert: in[R][Cc] f32 -> out[Cc][R] bf16 -----
__global__ __launch_bounds__(256) void transpose_cvt_k(const float* __restrict__ inv,
                                                       u16* __restrict__ out,
                                                       int R, int Cc){
  __shared__ u16 t[64][65];
  const int bx = blockIdx.x*64, by = blockIdx.y*64;
  const int tx = threadIdx.x & 63, ty = threadIdx.x >> 6;
  #pragma unroll
  for (int i = 0; i < 16; ++i){
    int r = ty + i*4;
    t[r][tx] = f2bf(inv[(size_t)(by+r)*Cc + bx+tx]);
  }
  __syncthreads();
  #pragma unroll
  for (int i = 0; i < 16; ++i){
    int r = ty + i*4;
    out[(size_t)(bx+r)*R + by+tx] = t[tx][r];
  }
}

// ---------------- GEMM (NT): C[M][N] = A[M][K]*BT[N][K]^T + bias ----------
// 128x128 tile, BK=64, 4 waves (64x64 each). of32: 1 = write float, 0 = bf16.
__global__ __launch_bounds__(256) void gemm_nt(const u16* __restrict__ A,
                                               const u16* __restrict__ BT,
                                               const float* __restrict__ bias,
                                               void* __restrict__ Cmat,
                                               int M, int N, int K, int of32){
  __shared__ u16 lA[128*64];
  __shared__ u16 lB[128*64];
  const int tid  = threadIdx.x;
  const int lane = tid & 63;
  const int wave = tid >> 6;
  const int bm = blockIdx.x, bn = blockIdx.y;
  const int wm = (wave >> 1) * 64;
  const int wn = (wave & 1) * 64;
  const int ln15 = lane & 15, g = lane >> 4;

  f32x4 acc[4][4];
  #pragma unroll
  for (int i = 0; i < 4; ++i)
    #pragma unroll
    for (int j = 0; j < 4; ++j) acc[i][j] = (f32x4){0.f,0.f,0.f,0.f};

  const int trow = tid >> 3;
  const int tc8s = (tid & 7) ^ (trow & 7);
  const size_t arow0 = (size_t)(bm*128) * K;
  const size_t brow0 = (size_t)(bn*128) * K;

  for (int k0 = 0; k0 < K; k0 += 64) {
    __syncthreads();
    #pragma unroll
    for (int c = 0; c < 4; ++c) {
      const int row = c*32 + trow;
      const size_t roff = (size_t)row*K + k0 + tc8s*8;
      gload16(A + arow0 + roff, (char*)lA + (c*256 + (wave<<6))*16);
      gload16(BT + brow0 + roff, (char*)lB + (c*256 + (wave<<6))*16);
    }
    asm volatile("s_waitcnt vmcnt(0)" ::: "memory");
    __syncthreads();

    short8 af[4][2], bfr[4][2];
    #pragma unroll
    for (int mf = 0; mf < 4; ++mf)
      #pragma unroll
      for (int kc = 0; kc < 2; ++kc) {
        const int r = wm + mf*16 + ln15;
        const int cb = (kc*64 + (g << 4)) ^ ((r & 7) << 4);
        af[mf][kc] = *(const short8*)((const char*)lA + r*128 + cb);
      }
    #pragma unroll
    for (int nf = 0; nf < 4; ++nf)
      #pragma unroll
      for (int kc = 0; kc < 2; ++kc) {
        const int r = wn + nf*16 + ln15;
        const int cb = (kc*64 + (g << 4)) ^ ((r & 7) << 4);
        bfr[nf][kc] = *(const short8*)((const char*)lB + r*128 + cb);
      }
    #pragma unroll
    for (int kc = 0; kc < 2; ++kc)
      #pragma unroll
      for (int mf = 0; mf < 4; ++mf)
        #pragma unroll
        for (int nf = 0; nf < 4; ++nf)
          acc[mf][nf] = mfma16x16x32(af[mf][kc], bfr[nf][kc], acc[mf][nf]);
  }

  #pragma unroll
  for (int nf = 0; nf < 4; ++nf) {
    const int col = bn*128 + wn + nf*16 + ln15;
    const float bv = bias[col];
    #pragma unroll
    for (int mf = 0; mf < 4; ++mf) {
      #pragma unroll
      for (int r = 0; r < 4; ++r) {
        const int rowg = bm*128 + wm + mf*16 + g*4 + r;
        const float v = acc[mf][nf][r] + bv;
        if (of32) ((float*)Cmat)[(size_t)rowg*N + col] = v;
        else      ((u16*)Cmat)[(size_t)rowg*N + col] = f2bf(v);
      }
    }
  }
}

// ---------------- causal flash attention (v2) ----------------
// grid: (T/128, B*H); block 512 = 8 waves; wave handles 16 q-rows.
// Single barrier per 64-key tile; K via global_load_lds (dbuf, swizzled);
// V prefetched to regs, written as V^T (scalar, swizzled) late (T14 split).
__global__ __launch_bounds__(512) void attn_k(const u16* __restrict__ qkv,
                                              u16* __restrict__ y){
  __shared__ u16 kb[2][64*64];    // [key][d], 128B rows, 16B-chunk XOR swizzle
  __shared__ u16 vb[2][64*72];    // [d][key], 144B rows, chunk-XOR swizzle
  __shared__ u16 pls[8][16*64];   // per-wave P [qrow][key], 128B rows, swizzled
  const int tid  = threadIdx.x;
  const int lane = tid & 63;
  const int wave = tid >> 6;
  const int qb = (gridDim.x - 1) - blockIdx.x;   // heavy blocks first
  const int bh = blockIdx.y;
  const int b = bh >> 4, h = bh & 15;
  const int ln15 = lane & 15, g = lane >> 4;
  const int q0 = qb*128 + wave*16;
  const size_t base = (size_t)b * TT * C3;

  // staging geometry (per thread): row = tid>>3 (0..63), chunk = tid&7
  const int srow = tid >> 3;
  const int sc8  = tid & 7;
  const u16* ksrc0 = qkv + base + CCx  + h*DD + ((sc8 ^ (srow & 7)) * 8);
  const u16* vsrc0 = qkv + base + 2*CCx + h*DD + sc8*8;
  char* plw = (char*)pls[wave];

  // Q fragments
  short8 qf[2];
  {
    const u16* qp = qkv + base + (size_t)(q0 + ln15)*C3 + h*DD + g*8;
    qf[0] = *(const short8*)qp;
    qf[1] = *(const short8*)(qp + 32);
  }

  f32x4 o[4]; float m[4], lsum[4];
  #pragma unroll
  for (int i = 0; i < 4; ++i){ o[i] = (f32x4){0.f,0.f,0.f,0.f}; m[i] = -1e30f; lsum[i] = 0.f; }

  const int nt = 2*qb + 2;

  // prologue: stage tile 0
  gload16(ksrc0 + (size_t)srow*C3, (char*)kb[0] + wave*1024);
  short8 vreg = *(const short8*)(vsrc0 + (size_t)srow*C3);
  asm volatile("s_waitcnt vmcnt(0)" ::: "memory");
  #pragma unroll
  for (int i = 0; i < 8; ++i){
    const int d = sc8*8 + i;
    *(u16*)((char*)vb[0] + d*144 + (((srow >> 3) ^ (d & 7)) << 4) + (srow & 7)*2) = (u16)vreg[i];
  }
  __syncthreads();

  int c = 0;
  for (int t = 0; t < nt; ++t){
    const int kv0 = t*64;
    const bool hn = (t + 1 < nt);
    if (hn){   // issue prefetch for tile t+1 (hides under compute)
      gload16(ksrc0 + (size_t)(kv0 + 64 + srow)*C3, (char*)kb[c^1] + wave*1024);
      vreg = *(const short8*)(vsrc0 + (size_t)(kv0 + 64 + srow)*C3);
    }

    if (kv0 <= q0 + 15){   // wave-uniform causal skip
      // QK^T from kb[c]
      const char* kbc = (const char*)kb[c];
      f32x4 s[4];
      #pragma unroll
      for (int kf = 0; kf < 4; ++kf){
        const int krow = kf*16 + ln15;
        short8 k0 = *(const short8*)(kbc + krow*128 + ((g*16)      ^ ((krow & 7)*16)));
        short8 k1 = *(const short8*)(kbc + krow*128 + ((64 + g*16) ^ ((krow & 7)*16)));
        f32x4 z = (f32x4){0.f,0.f,0.f,0.f};
        s[kf] = mfma16x16x32(qf[0], k0, z);
        s[kf] = mfma16x16x32(qf[1], k1, s[kf]);
      }

      // scale + causal mask + per-row max
      float sv[4][4];
      float tmax[4] = {-1e30f,-1e30f,-1e30f,-1e30f};
      #pragma unroll
      for (int kf = 0; kf < 4; ++kf){
        const int key = kv0 + kf*16 + ln15;
        #pragma unroll
        for (int r = 0; r < 4; ++r){
          const int q = q0 + g*4 + r;
          float v = s[kf][r] * 0.125f;
          v = (key <= q) ? v : -1e30f;
          sv[kf][r] = v;
          tmax[r] = fmaxf(tmax[r], v);
        }
      }
      #pragma unroll
      for (int r = 0; r < 4; ++r){
        float v = tmax[r];
        v = fmaxf(v, __shfl_xor(v, 1));
        v = fmaxf(v, __shfl_xor(v, 2));
        v = fmaxf(v, __shfl_xor(v, 4));
        v = fmaxf(v, __shfl_xor(v, 8));
        tmax[r] = v;
      }
      float fac[4], rsum[4];
      #pragma unroll
      for (int r = 0; r < 4; ++r){
        const float nm = fmaxf(m[r], tmax[r]);
        fac[r] = exp2f((m[r] - nm) * 1.44269504f);
        m[r] = nm;
        rsum[r] = 0.f;
      }
      // P = exp(S-m) -> bf16 into per-wave LDS (swizzled), accumulate sums
      #pragma unroll
      for (int kf = 0; kf < 4; ++kf)
        #pragma unroll
        for (int r = 0; r < 4; ++r){
          const float p = exp2f((sv[kf][r] - m[r]) * 1.44269504f);
          rsum[r] += p;
          const int qr = g*4 + r;
          const int col = kf*16 + ln15;
          *(u16*)(plw + qr*128 + (((col >> 3) ^ (qr & 7)) << 4) + (col & 7)*2) = f2bf(p);
        }
      #pragma unroll
      for (int r = 0; r < 4; ++r){
        float v = rsum[r];
        v += __shfl_xor(v, 1);
        v += __shfl_xor(v, 2);
        v += __shfl_xor(v, 4);
        v += __shfl_xor(v, 8);
        lsum[r] = lsum[r] * fac[r] + v;
        #pragma unroll
        for (int db = 0; db < 4; ++db) o[db][r] *= fac[r];
      }
      asm volatile("s_waitcnt lgkmcnt(0)" ::: "memory");
      __builtin_amdgcn_sched_barrier(0);

      // PV from vb[c]
      const char* vbc = (const char*)vb[c];
      #pragma unroll
      for (int kc = 0; kc < 2; ++kc){
        const int ch = kc*4 + g;
        short8 pa = *(const short8*)(plw + ln15*128 + ((ch ^ (ln15 & 7)) << 4));
        #pragma unroll
        for (int db = 0; db < 4; ++db){
          const int vd = db*16 + ln15;
          short8 vbr = *(const short8*)(vbc + vd*144 + ((ch ^ (vd & 7)) << 4));
          o[db] = mfma16x16x32(pa, vbr, o[db]);
        }
      }
    }

    if (hn){   // complete staging for t+1
      asm volatile("s_waitcnt vmcnt(0)" ::: "memory");
      #pragma unroll
      for (int i = 0; i < 8; ++i){
        const int d = sc8*8 + i;
        *(u16*)((char*)vb[c^1] + d*144 + (((srow >> 3) ^ (d & 7)) << 4) + (srow & 7)*2) = (u16)vreg[i];
      }
    }
    __syncthreads();
    c ^= 1;
  }

  // normalize and store y (bf16)
  float inv[4];
  #pragma unroll
  for (int r = 0; r < 4; ++r) inv[r] = 1.0f / lsum[r];
  #pragma unroll
  for (int db = 0; db < 4; ++db){
    #pragma unroll
    for (int r = 0; r < 4; ++r){
      y[(size_t)(b*TT + q0 + g*4 + r)*CCx + h*DD + db*16 + ln15] = f2bf(o[db][r] * inv[r]);
    }
  }
}

extern "C" void kernel_launch(void* const* d_in, const int* in_sizes, int n_in,
                              void* d_out, int out_size, void* d_ws, size_t ws_size,
                              hipStream_t stream) {
  const float *x = nullptr, *w_attn = nullptr, *b_attn = nullptr,
              *w_proj = nullptr, *b_proj = nullptr;
  for (int i = 0; i < n_in; ++i) {
    switch (in_sizes[i]) {
      case MM*CCx:  x      = (const float*)d_in[i]; break;
      case C3*CCx:  w_attn = (const float*)d_in[i]; break;
      case C3:      b_attn = (const float*)d_in[i]; break;
      case CCx*CCx: w_proj = (const float*)d_in[i]; break;
      case CCx:     b_proj = (const float*)d_in[i]; break;
    }
  }
  float* out = (float*)d_out;

  char* ws = (char*)d_ws;
  u16* xb      = (u16*)ws;
  u16* wT_attn = xb + (size_t)MM*CCx;
  u16* wT_proj = wT_attn + (size_t)C3*CCx;
  u16* qkv     = wT_proj + (size_t)CCx*CCx;
  u16* ybuf    = qkv + (size_t)MM*C3;

  cvt_x_k<<<(MM*CCx/8 + 255)/256, 256, 0, stream>>>(x, xb, MM*CCx/8);
  transpose_cvt_k<<<dim3(C3/64, CCx/64), 256, 0, stream>>>(w_attn, wT_attn, CCx, C3);
  transpose_cvt_k<<<dim3(CCx/64, CCx/64), 256, 0, stream>>>(w_proj, wT_proj, CCx, CCx);
  gemm_nt<<<dim3(MM/128, C3/128), 256, 0, stream>>>(xb, wT_attn, b_attn, qkv, MM, C3, CCx, 0);
  attn_k<<<dim3(TT/128, BB*HH), 512, 0, stream>>>(qkv, ybuf);
  gemm_nt<<<dim3(MM/128, CCx/128), 256, 0, stream>>>(ybuf, wT_proj, b_proj, out, MM, CCx, CCx, 1);
}

// Round 8
// 173.561 us; speedup vs baseline: 1.8043x; 1.2193x over previous
//
#include <hip/hip_runtime.h>
#include <stdint.h>

#define BB 2
#define TT 2048
#define CCx 1024
#define HH 16
#define DD 64
#define MM (BB*TT)      // 4096
#define C3 (3*CCx)      // 3072

using u16 = unsigned short;
typedef __attribute__((ext_vector_type(8))) short short8;
typedef __attribute__((ext_vector_type(4))) float f32x4;

__device__ __forceinline__ float bf2f(u16 u){
  union { unsigned int i; float f; } v; v.i = ((unsigned int)u) << 16; return v.f;
}
__device__ __forceinline__ u16 f2bf(float f){
  union { float f; unsigned int u; } v; v.f = f;
  unsigned int r = v.u + 0x7fffu + ((v.u >> 16) & 1u);
  return (u16)(r >> 16);
}

// D = A(16x32)*B(32x16)+C, bf16 in, fp32 out.
// A-frag: lane holds A[lane&15][8*(lane>>4)+i]; B-frag: lane holds B[8g+i][lane&15]
// C/D: lane holds D[4*(lane>>4)+r][lane&15]
__device__ __forceinline__ f32x4 mfma16x16x32(short8 a, short8 b, f32x4 c){
  return __builtin_amdgcn_mfma_f32_16x16x32_bf16(a, b, c, 0, 0, 0);
}

typedef __attribute__((address_space(1))) unsigned int gu32;
typedef __attribute__((address_space(3))) unsigned int su32;
__device__ __forceinline__ void gload16(const void* g, void* l){
  __builtin_amdgcn_global_load_lds((gu32*)g, (su32*)l, 16, 0, 0);
}

// ---------------- x convert: f32 -> bf16 ----------------
__global__ __launch_bounds__(256) void cvt_x_k(const float* __restrict__ inv,
                                               u16* __restrict__ out, int n8){
  int i = blockIdx.x*256 + threadIdx.x;
  if (i >= n8) return;
  const float* p = inv + (size_t)i*8;
  float4 a = *(const float4*)p, b = *(const float4*)(p+4);
  short8 v;
  v[0]=(short)f2bf(a.x); v[1]=(short)f2bf(a.y); v[2]=(short)f2bf(a.z); v[3]=(short)f2bf(a.w);
  v[4]=(short)f2bf(b.x); v[5]=(short)f2bf(b.y); v[6]=(short)f2bf(b.z); v[7]=(short)f2bf(b.w);
  *(short8*)(out + (size_t)i*8) = v;
}

// ------- padded transpose+convert: in[R][Cc] f32 -> out[Cc][R] bf16 -----
__global__ __launch_bounds__(256) void transpose_cvt_k(const float* __restrict__ inv,
                                                       u16* __restrict__ out,
                                                       int R, int Cc){
  __shared__ u16 t[64][65];
  const int bx = blockIdx.x*64, by = blockIdx.y*64;
  const int tx = threadIdx.x & 63, ty = threadIdx.x >> 6;
  #pragma unroll
  for (int i = 0; i < 16; ++i){
    int r = ty + i*4;
    t[r][tx] = f2bf(inv[(size_t)(by+r)*Cc + bx+tx]);
  }
  __syncthreads();
  #pragma unroll
  for (int i = 0; i < 16; ++i){
    int r = ty + i*4;
    out[(size_t)(bx+r)*R + by+tx] = t[tx][r];
  }
}

// ---------------- GEMM (NT): C[M][N] = A[M][K]*BT[N][K]^T + bias ----------
__global__ __launch_bounds__(256) void gemm_nt(const u16* __restrict__ A,
                                               const u16* __restrict__ BT,
                                               const float* __restrict__ bias,
                                               void* __restrict__ Cmat,
                                               int M, int N, int K, int of32){
  __shared__ u16 lA[128*64];
  __shared__ u16 lB[128*64];
  const int tid  = threadIdx.x;
  const int lane = tid & 63;
  const int wave = tid >> 6;
  const int bm = blockIdx.x, bn = blockIdx.y;
  const int wm = (wave >> 1) * 64;
  const int wn = (wave & 1) * 64;
  const int ln15 = lane & 15, g = lane >> 4;

  f32x4 acc[4][4];
  #pragma unroll
  for (int i = 0; i < 4; ++i)
    #pragma unroll
    for (int j = 0; j < 4; ++j) acc[i][j] = (f32x4){0.f,0.f,0.f,0.f};

  const int trow = tid >> 3;
  const int tc8s = (tid & 7) ^ (trow & 7);
  const size_t arow0 = (size_t)(bm*128) * K;
  const size_t brow0 = (size_t)(bn*128) * K;

  for (int k0 = 0; k0 < K; k0 += 64) {
    __syncthreads();
    #pragma unroll
    for (int c = 0; c < 4; ++c) {
      const int row = c*32 + trow;
      const size_t roff = (size_t)row*K + k0 + tc8s*8;
      gload16(A + arow0 + roff, (char*)lA + (c*256 + (wave<<6))*16);
      gload16(BT + brow0 + roff, (char*)lB + (c*256 + (wave<<6))*16);
    }
    asm volatile("s_waitcnt vmcnt(0)" ::: "memory");
    __syncthreads();

    short8 af[4][2], bfr[4][2];
    #pragma unroll
    for (int mf = 0; mf < 4; ++mf)
      #pragma unroll
      for (int kc = 0; kc < 2; ++kc) {
        const int r = wm + mf*16 + ln15;
        const int cb = (kc*64 + (g << 4)) ^ ((r & 7) << 4);
        af[mf][kc] = *(const short8*)((const char*)lA + r*128 + cb);
      }
    #pragma unroll
    for (int nf = 0; nf < 4; ++nf)
      #pragma unroll
      for (int kc = 0; kc < 2; ++kc) {
        const int r = wn + nf*16 + ln15;
        const int cb = (kc*64 + (g << 4)) ^ ((r & 7) << 4);
        bfr[nf][kc] = *(const short8*)((const char*)lB + r*128 + cb);
      }
    #pragma unroll
    for (int kc = 0; kc < 2; ++kc)
      #pragma unroll
      for (int mf = 0; mf < 4; ++mf)
        #pragma unroll
        for (int nf = 0; nf < 4; ++nf)
          acc[mf][nf] = mfma16x16x32(af[mf][kc], bfr[nf][kc], acc[mf][nf]);
  }

  #pragma unroll
  for (int nf = 0; nf < 4; ++nf) {
    const int col = bn*128 + wn + nf*16 + ln15;
    const float bv = bias[col];
    #pragma unroll
    for (int mf = 0; mf < 4; ++mf) {
      #pragma unroll
      for (int r = 0; r < 4; ++r) {
        const int rowg = bm*128 + wm + mf*16 + g*4 + r;
        const float v = acc[mf][nf][r] + bv;
        if (of32) ((float*)Cmat)[(size_t)rowg*N + col] = v;
        else      ((u16*)Cmat)[(size_t)rowg*N + col] = f2bf(v);
      }
    }
  }
}

// ---------------- causal flash attention (v3: balanced pairing) ----------------
// grid: (16, B*H); block 512 = 8 waves. Waves 0-3 own q-tile jb (64 rows),
// waves 4-7 own q-tile 31-jb. K/V 64-key tiles staged once, shared.
// Uniform compute: (jb+1)+(32-jb) = 33 wave-tile-units per block.
#define LOG2E_S 0.1803369f   // log2(e) * 0.125
__global__ __launch_bounds__(512) void attn_k(const u16* __restrict__ qkv,
                                              u16* __restrict__ y){
  __shared__ u16 kb[2][64*64];    // [key][d], 128B rows, 16B-chunk XOR swizzle
  __shared__ u16 vb[2][64*72];    // [d][key], 144B rows, chunk-XOR swizzle
  __shared__ u16 pls[8][16*64];   // per-wave P [qrow][key], 128B rows, swizzled
  const int tid  = threadIdx.x;
  const int lane = tid & 63;
  const int wave = tid >> 6;
  const int jb = blockIdx.x;            // 0..15; jb=0 = longest, launches first
  const int bh = blockIdx.y;
  const int b = bh >> 4, h = bh & 15;
  const int ln15 = lane & 15, g = lane >> 4;
  const int sub = wave >> 2;            // 0 = lo q-tile, 1 = hi q-tile
  const int wq  = wave & 3;
  const int jq  = sub ? (31 - jb) : jb;
  const int q0  = jq*64 + wq*16;
  const int ntw = sub ? (32 - jb) : (jb + 1);   // tiles this wave computes
  const int nt  = 32 - jb;                       // staging loop length
  const size_t base = (size_t)b * TT * C3;

  // staging geometry: row = tid>>3 (0..63), chunk = tid&7
  const int srow = tid >> 3;
  const int sc8  = tid & 7;
  const u16* ksrc0 = qkv + base + CCx   + h*DD + ((sc8 ^ (srow & 7)) * 8);
  const u16* vsrc0 = qkv + base + 2*CCx + h*DD + sc8*8;
  char* plw = (char*)pls[wave];

  // Q fragments
  short8 qf[2];
  {
    const u16* qp = qkv + base + (size_t)(q0 + ln15)*C3 + h*DD + g*8;
    qf[0] = *(const short8*)qp;
    qf[1] = *(const short8*)(qp + 32);
  }

  f32x4 o[4]; float m[4], lsum[4];
  #pragma unroll
  for (int i = 0; i < 4; ++i){ o[i] = (f32x4){0.f,0.f,0.f,0.f}; m[i] = -1e30f; lsum[i] = 0.f; }

  // prologue: stage tile 0
  gload16(ksrc0 + (size_t)srow*C3, (char*)kb[0] + wave*1024);
  short8 vreg = *(const short8*)(vsrc0 + (size_t)srow*C3);
  asm volatile("s_waitcnt vmcnt(0)" ::: "memory");
  #pragma unroll
  for (int i = 0; i < 8; ++i){
    const int d = sc8*8 + i;
    *(u16*)((char*)vb[0] + d*144 + (((srow >> 3) ^ (d & 7)) << 4) + (srow & 7)*2) = (u16)vreg[i];
  }
  __syncthreads();

  int c = 0;
  for (int t = 0; t < nt; ++t){
    const int kv0 = t*64;
    const bool hn = (t + 1 < nt);
    if (hn){   // issue prefetch for tile t+1
      gload16(ksrc0 + (size_t)(kv0 + 64 + srow)*C3, (char*)kb[c^1] + wave*1024);
      vreg = *(const short8*)(vsrc0 + (size_t)(kv0 + 64 + srow)*C3);
    }

    if (t < ntw){   // wave-uniform: this wave's causal range
      // QK^T from kb[c] (raw scores; scale fused into exp)
      const char* kbc = (const char*)kb[c];
      f32x4 s[4];
      #pragma unroll
      for (int kf = 0; kf < 4; ++kf){
        const int krow = kf*16 + ln15;
        short8 k0 = *(const short8*)(kbc + krow*128 + ((g*16)      ^ ((krow & 7)*16)));
        short8 k1 = *(const short8*)(kbc + krow*128 + ((64 + g*16) ^ ((krow & 7)*16)));
        f32x4 z = (f32x4){0.f,0.f,0.f,0.f};
        s[kf] = mfma16x16x32(qf[0], k0, z);
        s[kf] = mfma16x16x32(qf[1], k1, s[kf]);
      }

      // causal mask + per-row raw max
      float sv[4][4];
      float tmax[4] = {-1e30f,-1e30f,-1e30f,-1e30f};
      #pragma unroll
      for (int kf = 0; kf < 4; ++kf){
        const int key = kv0 + kf*16 + ln15;
        #pragma unroll
        for (int r = 0; r < 4; ++r){
          const int q = q0 + g*4 + r;
          float v = (key <= q) ? s[kf][r] : -1e30f;
          sv[kf][r] = v;
          tmax[r] = fmaxf(tmax[r], v);
        }
      }
      #pragma unroll
      for (int r = 0; r < 4; ++r){
        float v = tmax[r];
        v = fmaxf(v, __shfl_xor(v, 1));
        v = fmaxf(v, __shfl_xor(v, 2));
        v = fmaxf(v, __shfl_xor(v, 4));
        v = fmaxf(v, __shfl_xor(v, 8));
        tmax[r] = v;
      }
      // defer-max: rescale only when max grew by > 64 raw (= 8 scaled)
      bool need = false;
      #pragma unroll
      for (int r = 0; r < 4; ++r) need |= (tmax[r] > m[r] + 64.f);
      if (__any(need)){
        #pragma unroll
        for (int r = 0; r < 4; ++r){
          const float nm = fmaxf(m[r], tmax[r]);
          const float fac = exp2f((m[r] - nm) * LOG2E_S);
          m[r] = nm; lsum[r] *= fac;
          #pragma unroll
          for (int db = 0; db < 4; ++db) o[db][r] *= fac;
        }
      }
      // P = exp2(fma(s, LOG2E_S, -m*LOG2E_S)) -> bf16 pairs via cvt_pk
      float mm[4], rsum[4];
      #pragma unroll
      for (int r = 0; r < 4; ++r){ mm[r] = m[r]*LOG2E_S; rsum[r] = 0.f; }
      #pragma unroll
      for (int r = 0; r < 4; ++r){
        const int qr = g*4 + r;
        char* rowp = plw + qr*128;
        const int swz = qr & 7;
        #pragma unroll
        for (int pk = 0; pk < 2; ++pk){
          const float pa_ = exp2f(fmaf(sv[2*pk][r],   LOG2E_S, -mm[r]));
          const float pb_ = exp2f(fmaf(sv[2*pk+1][r], LOG2E_S, -mm[r]));
          rsum[r] += pa_ + pb_;
          unsigned w;
          asm("v_cvt_pk_bf16_f32 %0, %1, %2" : "=v"(w) : "v"(pa_), "v"(pb_));
          const int hi8 = ln15 >> 3, lo7 = (ln15 & 7)*2;
          *(u16*)(rowp + (((4*pk   + hi8) ^ swz) << 4) + lo7) = (u16)w;
          *(u16*)(rowp + (((4*pk+2 + hi8) ^ swz) << 4) + lo7) = (u16)(w >> 16);
        }
      }
      #pragma unroll
      for (int r = 0; r < 4; ++r){
        float v = rsum[r];
        v += __shfl_xor(v, 1);
        v += __shfl_xor(v, 2);
        v += __shfl_xor(v, 4);
        v += __shfl_xor(v, 8);
        lsum[r] += v;
      }
      asm volatile("s_waitcnt lgkmcnt(0)" ::: "memory");
      __builtin_amdgcn_sched_barrier(0);

      // PV from vb[c]
      const char* vbc = (const char*)vb[c];
      #pragma unroll
      for (int kc = 0; kc < 2; ++kc){
        const int ch = kc*4 + g;
        short8 pa = *(const short8*)(plw + ln15*128 + ((ch ^ (ln15 & 7)) << 4));
        #pragma unroll
        for (int db = 0; db < 4; ++db){
          const int vd = db*16 + ln15;
          short8 vbr = *(const short8*)(vbc + vd*144 + ((ch ^ (vd & 7)) << 4));
          o[db] = mfma16x16x32(pa, vbr, o[db]);
        }
      }
    }

    if (hn){   // complete V staging for t+1
      asm volatile("s_waitcnt vmcnt(0)" ::: "memory");
      #pragma unroll
      for (int i = 0; i < 8; ++i){
        const int d = sc8*8 + i;
        *(u16*)((char*)vb[c^1] + d*144 + (((srow >> 3) ^ (d & 7)) << 4) + (srow & 7)*2) = (u16)vreg[i];
      }
    }
    __syncthreads();
    c ^= 1;
  }

  // normalize and store y (bf16)
  float inv[4];
  #pragma unroll
  for (int r = 0; r < 4; ++r) inv[r] = 1.0f / lsum[r];
  #pragma unroll
  for (int db = 0; db < 4; ++db){
    #pragma unroll
    for (int r = 0; r < 4; ++r){
      y[(size_t)(b*TT + q0 + g*4 + r)*CCx + h*DD + db*16 + ln15] = f2bf(o[db][r] * inv[r]);
    }
  }
}

extern "C" void kernel_launch(void* const* d_in, const int* in_sizes, int n_in,
                              void* d_out, int out_size, void* d_ws, size_t ws_size,
                              hipStream_t stream) {
  const float *x = nullptr, *w_attn = nullptr, *b_attn = nullptr,
              *w_proj = nullptr, *b_proj = nullptr;
  for (int i = 0; i < n_in; ++i) {
    switch (in_sizes[i]) {
      case MM*CCx:  x      = (const float*)d_in[i]; break;
      case C3*CCx:  w_attn = (const float*)d_in[i]; break;
      case C3:      b_attn = (const float*)d_in[i]; break;
      case CCx*CCx: w_proj = (const float*)d_in[i]; break;
      case CCx:     b_proj = (const float*)d_in[i]; break;
    }
  }
  float* out = (float*)d_out;

  char* ws = (char*)d_ws;
  u16* xb      = (u16*)ws;
  u16* wT_attn = xb + (size_t)MM*CCx;
  u16* wT_proj = wT_attn + (size_t)C3*CCx;
  u16* qkv     = wT_proj + (size_t)CCx*CCx;
  u16* ybuf    = qkv + (size_t)MM*C3;

  cvt_x_k<<<(MM*CCx/8 + 255)/256, 256, 0, stream>>>(x, xb, MM*CCx/8);
  transpose_cvt_k<<<dim3(C3/64, CCx/64), 256, 0, stream>>>(w_attn, wT_attn, CCx, C3);
  transpose_cvt_k<<<dim3(CCx/64, CCx/64), 256, 0, stream>>>(w_proj, wT_proj, CCx, CCx);
  gemm_nt<<<dim3(MM/128, C3/128), 256, 0, stream>>>(xb, wT_attn, b_attn, qkv, MM, C3, CCx, 0);
  attn_k<<<dim3(16, BB*HH), 512, 0, stream>>>(qkv, ybuf);
  gemm_nt<<<dim3(MM/128, CCx/128), 256, 0, stream>>>(ybuf, wT_proj, b_proj, out, MM, CCx, CCx, 1);
}